// Round 2
// baseline (25201.561 us; speedup 1.0000x reference)
//
#include <hip/hip_runtime.h>
#include <hip/hip_bf16.h>
#include <cstdio>
#include <math.h>

// ---------------------------------------------------------------------------
// StyleGANv2 generator forward. bf16 storage + fp32 accumulation.
//
// Refactor: modulated+demodulated conv == d[b,o] * conv(x * s'[b,i], w_shared)
//   s'_conv[b,i] = (wlat[b]·style_w[i]/sqrt(512) + style_b[i]) / sqrt(512*9)
//   d[b,o]      = rsqrt( sum_i s'^2 * wsq[o,i] + 1e-8 ),  wsq = sum_taps w^2
// Up-conv (convT stride2 k3) == gather with parity predicate over 9 taps.
// Blur = 4x4 FIR outer([1,3,3,1])/16. Activations channel-last (B,H,W,C).
// ---------------------------------------------------------------------------

static constexpr int NB = 32;
static constexpr float SQRT2F      = 1.41421356237309515f;
static constexpr float INV_SQRT512 = 0.04419417382415922f;   // 1/sqrt(512)
static constexpr float INV_SQRT4608= 0.014731391274719742f;  // 1/sqrt(512*9)

typedef __hip_bfloat16 bf16;

__device__ __forceinline__ float lrelu_s2(float v){ return (v > 0.f ? v : 0.2f*v) * SQRT2F; }
__device__ __forceinline__ float bf_lo(unsigned u){ unsigned v = u << 16; return __builtin_bit_cast(float, v); }
__device__ __forceinline__ float bf_hi(unsigned u){ unsigned v = u & 0xffff0000u; return __builtin_bit_cast(float, v); }
__device__ __forceinline__ unsigned packbf2(float a, float b){
  bf16 ha = __float2bfloat16(a), hb = __float2bfloat16(b);
  unsigned short ra = __builtin_bit_cast(unsigned short, ha);
  unsigned short rb = __builtin_bit_cast(unsigned short, hb);
  return (unsigned)ra | ((unsigned)rb << 16);
}

// ---------------- mapping network: pixel_norm + 8x (512x512 lrelu) ----------
__global__ void k_mapping(const float* __restrict__ z, const float* __restrict__ mlp_w,
                          const float* __restrict__ mlp_b, float* __restrict__ wlat){
  __shared__ float xb[512], yb[512], red[256];
  int b = blockIdx.x, t = threadIdx.x;
  float z0 = z[b*512 + t], z1 = z[b*512 + t + 256];
  red[t] = z0*z0 + z1*z1;
  __syncthreads();
  for(int s = 128; s > 0; s >>= 1){ if(t < s) red[t] += red[t+s]; __syncthreads(); }
  float norm = sqrtf(red[0]) * INV_SQRT512;
  float inv = 1.f / (norm + 1e-6f);
  xb[t] = z0*inv; xb[t+256] = z1*inv;
  __syncthreads();
  for(int l = 0; l < 8; l++){
    const float* Wl = mlp_w + (size_t)l*512*512;
    const float* bl = mlp_b + l*512;
    for(int oo = 0; oo < 2; oo++){
      int o = t + oo*256;
      const float4* wr = (const float4*)(Wl + (size_t)o*512);
      float acc = 0.f;
      #pragma unroll 4
      for(int k = 0; k < 128; k++){
        float4 w4 = wr[k];
        acc += w4.x*xb[4*k] + w4.y*xb[4*k+1] + w4.z*xb[4*k+2] + w4.w*xb[4*k+3];
      }
      yb[o] = lrelu_s2(acc*INV_SQRT512 + bl[o]*0.01f);
    }
    __syncthreads();
    xb[t] = yb[t]; xb[t+256] = yb[t+256];
    __syncthreads();
  }
  wlat[b*512+t] = xb[t]; wlat[b*512+t+256] = xb[t+256];
}

// ---------------- styles: s' for 9 conv layers + 5 torgb layers -------------
__global__ void k_styles(const float* __restrict__ wlat,
                         const float* __restrict__ csw, const float* __restrict__ csb,
                         const float* __restrict__ tsw, const float* __restrict__ tsb,
                         float* __restrict__ s_conv, float* __restrict__ s_trgb){
  int gid = blockIdx.x*256 + threadIdx.x;        // 14*32*512 = 229376 exactly
  int l = gid >> 14;
  int b = (gid >> 9) & 31;
  int i = gid & 511;
  const float* row; float bias, wsc;
  if(l < 9){ row = csw + ((size_t)l*512 + i)*512; bias = csb[l*512+i]; wsc = INV_SQRT4608; }
  else     { int lt = l-9; row = tsw + ((size_t)lt*512 + i)*512; bias = tsb[lt*512+i]; wsc = INV_SQRT512; }
  const float4* r4 = (const float4*)row;
  const float4* w4 = (const float4*)(wlat + b*512);
  float acc = 0.f;
  #pragma unroll 4
  for(int k = 0; k < 128; k++){
    float4 a = w4[k], c = r4[k];
    acc += a.x*c.x + a.y*c.y + a.z*c.z + a.w*c.w;
  }
  float s = (acc*INV_SQRT512 + bias) * wsc;
  if(l < 9) s_conv[((size_t)l*32 + b)*512 + i] = s;
  else      s_trgb[((size_t)(l-9)*32 + b)*512 + i] = s;
}

// ---------------- wsq[l,o,i] = sum over 9 taps of w^2 -----------------------
__global__ void k_wsq(const float* __restrict__ cw, float* __restrict__ wsq){
  int gid = blockIdx.x*256 + threadIdx.x;        // 9*512*512 = 2359296 exactly
  const float* p = cw + (size_t)gid*9;
  float a = 0.f;
  #pragma unroll
  for(int t = 0; t < 9; t++){ float v = p[t]; a += v*v; }
  wsq[gid] = a;
}

// ---------------- demod d[l,b,o] ---------------------------------------------
__global__ void k_demod(const float* __restrict__ s_conv, const float* __restrict__ wsq,
                        float* __restrict__ d_conv){
  __shared__ float s2[512];
  int l = blockIdx.x/32, b = blockIdx.x%32, t = threadIdx.x;
  size_t base = ((size_t)l*32 + b)*512;
  float v0 = s_conv[base + t], v1 = s_conv[base + t + 256];
  s2[t] = v0*v0; s2[t+256] = v1*v1;
  __syncthreads();
  for(int oo = 0; oo < 2; oo++){
    int o = t + oo*256;
    const float4* wr = (const float4*)(wsq + ((size_t)l*512 + o)*512);
    float acc = 0.f;
    #pragma unroll 4
    for(int k = 0; k < 128; k++){
      float4 w = wr[k];
      acc += w.x*s2[4*k] + w.y*s2[4*k+1] + w.z*s2[4*k+2] + w.w*s2[4*k+3];
    }
    d_conv[base + o] = rsqrtf(acc + 1e-8f);
  }
}

// ---------------- weight transpose: wT[l][tap][i][o] = cw[l][o][i][tap] ------
__global__ void k_wT(const float* __restrict__ cw, bf16* __restrict__ wT){
  __shared__ float tl[32][289];
  int l = blockIdx.z, o0 = blockIdx.y*32, i0 = blockIdx.x*32, t = threadIdx.x;
  for(int k = 0; k < 36; k++){
    int f = t + k*256; int o = f/288, j = f%288;
    tl[o][j] = cw[ (((size_t)l*512 + o0 + o)*512 + i0)*9 + j ];
  }
  __syncthreads();
  for(int k = 0; k < 36; k++){
    int g = t + k*256; int row = g/32, o = g%32; int i = row/9, tap = row%9;
    wT[ (((size_t)l*9 + tap)*512 + i0 + i)*512 + o0 + o ] = __float2bfloat16(tl[o][row]);
  }
}

// ---------------- const input tile -> act0 (B,4,4,512) ----------------------
__global__ void k_init(const float* __restrict__ ci, bf16* __restrict__ act){
  int gid = blockIdx.x*256 + threadIdx.x;        // 32*16*512 = 262144 exactly
  int c = gid & 511; int px = (gid >> 9) & 15;
  act[gid] = __float2bfloat16(ci[c*16 + px]);
}

// ---------------- main conv: implicit GEMM, 128x128 tile, 8x8 micro ----------
// UP=false: 3x3 pad1 conv at res Hin; EPI applies d,noise,bias,act.
// UP=true : transposed conv (parity gather), output (2Hin+1)^2, x d only.
template<bool UP, bool EPI>
__global__ __launch_bounds__(256)
void k_conv(const bf16* __restrict__ act, const bf16* __restrict__ wT,
            const float* __restrict__ sC, const float* __restrict__ dC,
            const float* __restrict__ noise, const float* __restrict__ nw_all,
            const float* __restrict__ ab_all, bf16* __restrict__ outp,
            int Hin, int layer){
  const int OH = UP ? (2*Hin + 1) : Hin;
  const int OHOH = OH*OH;
  const int Mtot = NB*OHOH;
  __shared__ float As[16][128];
  __shared__ float Bs[16][128];
  const int t = threadIdx.x;
  const int mbase = blockIdx.x*128;
  const int nbase = blockIdx.y*128;
  const float* sL = sC + (size_t)layer*NB*512;
  const float* dL = dC + (size_t)layer*NB*512;
  const bf16*  wL = wT + (size_t)layer*9*512*512;

  float acc[8][8];
  #pragma unroll
  for(int i = 0; i < 8; i++)
    #pragma unroll
    for(int j = 0; j < 8; j++) acc[i][j] = 0.f;

  int pixA[2]; pixA[0] = t >> 2; pixA[1] = (t >> 2) + 64;
  const int part = t & 3;
  int gb[2], gY[2], gX[2]; bool pvalid[2];
  #pragma unroll
  for(int q = 0; q < 2; q++){
    int m = mbase + pixA[q];
    pvalid[q] = (m < Mtot);
    int mm = pvalid[q] ? m : 0;
    gb[q] = mm / OHOH; int rem = mm % OHOH; gY[q] = rem / OH; gX[q] = rem % OH;
  }
  const int row_g = (t >> 4)*8;
  const int col_g = (t & 15)*8;
  const int brr = t >> 4, bcb = (t & 15)*8;

  for(int tap = 0; tap < 9; tap++){
    const int dy = tap/3, dx = tap%3;
    for(int icc = 0; icc < 512; icc += 16){
      __syncthreads();
      #pragma unroll
      for(int q = 0; q < 2; q++){
        float4 v = make_float4(0.f,0.f,0.f,0.f);
        int ic = icc + part*4;
        if(pvalid[q]){
          bool ok; int yy, xx;
          if(UP){
            int ty = gY[q] - dy, tx = gX[q] - dx;
            ok = (ty >= 0) && (tx >= 0) && !(ty & 1) && !(tx & 1);
            yy = ty >> 1; xx = tx >> 1;
            ok = ok && (yy < Hin) && (xx < Hin);
          } else {
            yy = gY[q] + dy - 1; xx = gX[q] + dx - 1;
            ok = (yy >= 0) && (yy < Hin) && (xx >= 0) && (xx < Hin);
          }
          if(ok){
            const bf16* src = act + ((size_t)((gb[q]*Hin + yy)*Hin + xx) << 9) + ic;
            uint2 u2 = *(const uint2*)src;
            float4 s4 = *(const float4*)(sL + gb[q]*512 + ic);
            v.x = bf_lo(u2.x)*s4.x; v.y = bf_hi(u2.x)*s4.y;
            v.z = bf_lo(u2.y)*s4.z; v.w = bf_hi(u2.y)*s4.w;
          }
        }
        int p = pixA[q], k0 = part*4;
        As[k0+0][p] = v.x; As[k0+1][p] = v.y; As[k0+2][p] = v.z; As[k0+3][p] = v.w;
      }
      {
        const bf16* src = wL + ((size_t)(tap*512 + icc + brr) << 9) + nbase + bcb;
        uint4 u4 = *(const uint4*)src;
        Bs[brr][bcb+0] = bf_lo(u4.x); Bs[brr][bcb+1] = bf_hi(u4.x);
        Bs[brr][bcb+2] = bf_lo(u4.y); Bs[brr][bcb+3] = bf_hi(u4.y);
        Bs[brr][bcb+4] = bf_lo(u4.z); Bs[brr][bcb+5] = bf_hi(u4.z);
        Bs[brr][bcb+6] = bf_lo(u4.w); Bs[brr][bcb+7] = bf_hi(u4.w);
      }
      __syncthreads();
      #pragma unroll
      for(int kk = 0; kk < 16; kk++){
        float4 a0 = *(const float4*)&As[kk][row_g];
        float4 a1 = *(const float4*)&As[kk][row_g+4];
        float4 b0 = *(const float4*)&Bs[kk][col_g];
        float4 b1 = *(const float4*)&Bs[kk][col_g+4];
        float a[8] = {a0.x,a0.y,a0.z,a0.w,a1.x,a1.y,a1.z,a1.w};
        float bb[8] = {b0.x,b0.y,b0.z,b0.w,b1.x,b1.y,b1.z,b1.w};
        #pragma unroll
        for(int mi = 0; mi < 8; mi++)
          #pragma unroll
          for(int ni = 0; ni < 8; ni++)
            acc[mi][ni] += a[mi]*bb[ni];
      }
    }
  }
  // epilogue
  const float nw = EPI ? nw_all[layer] : 0.f;
  #pragma unroll
  for(int mi = 0; mi < 8; mi++){
    int m = mbase + row_g + mi;
    if(m >= Mtot) continue;
    int b = m / OHOH; int rem = m % OHOH; int Y = rem / OH, X = rem % OH;
    float nz = EPI ? nw * noise[(b*OH + Y)*OH + X] : 0.f;
    bf16* op = outp + ((size_t)m << 9) + nbase + col_g;
    float vals[8];
    #pragma unroll
    for(int ni = 0; ni < 8; ni++){
      int o = nbase + col_g + ni;
      float val = acc[mi][ni] * dL[b*512 + o];
      if(EPI){ val += nz + ab_all[layer*512 + o]; val = lrelu_s2(val); }
      vals[ni] = val;
    }
    uint4 pk;
    pk.x = packbf2(vals[0], vals[1]); pk.y = packbf2(vals[2], vals[3]);
    pk.z = packbf2(vals[4], vals[5]); pk.w = packbf2(vals[6], vals[7]);
    *(uint4*)op = pk;
  }
}

// ---------------- 4x4 blur (u:(B,U,U,512) -> act:(B,O,O,512)) + noise + act --
__global__ void k_blur(const bf16* __restrict__ u, const float* __restrict__ noise,
                       const float* __restrict__ nw_all, const float* __restrict__ ab_all,
                       bf16* __restrict__ act, int O, int layer){
  const int U = O + 1;
  size_t gid = (size_t)blockIdx.x*256 + threadIdx.x;
  size_t total = (size_t)NB*O*O*128;
  if(gid >= total) return;
  int c4 = gid & 127;
  size_t pix = gid >> 7;
  int X = pix % O; int Y = (pix/O) % O; int b = pix/((size_t)O*O);
  const float k1[4] = {1.f, 3.f, 3.f, 1.f};
  float4 a = make_float4(0.f,0.f,0.f,0.f);
  #pragma unroll
  for(int ky = 0; ky < 4; ky++){
    int yy = Y + ky - 1; if(yy < 0 || yy >= U) continue;
    #pragma unroll
    for(int kx = 0; kx < 4; kx++){
      int xx = X + kx - 1; if(xx < 0 || xx >= U) continue;
      float w = k1[ky]*k1[kx]*(1.f/16.f);
      uint2 u2 = *(const uint2*)(u + (((size_t)(b*U + yy)*U + xx) << 9) + c4*4);
      a.x += w*bf_lo(u2.x); a.y += w*bf_hi(u2.x);
      a.z += w*bf_lo(u2.y); a.w += w*bf_hi(u2.y);
    }
  }
  float nz = nw_all[layer] * noise[(b*O + Y)*O + X];
  const float* ab = ab_all + layer*512 + c4*4;
  uint2 pk;
  pk.x = packbf2(lrelu_s2(a.x + nz + ab[0]), lrelu_s2(a.y + nz + ab[1]));
  pk.y = packbf2(lrelu_s2(a.z + nz + ab[2]), lrelu_s2(a.w + nz + ab[3]));
  *(uint2*)(act + (pix << 9) + c4*4) = pk;
}

// ---------------- toRGB (1x1 mod conv, no demod) -> NCHW skip ----------------
__global__ void k_torgb(const bf16* __restrict__ act, const float* __restrict__ tw,
                        const float* __restrict__ sT, const float* __restrict__ tbias,
                        float* __restrict__ dst, int H, int lt, int addflag){
  int wid = threadIdx.x >> 6, lane = threadIdx.x & 63;
  int pix = blockIdx.x*4 + wid;
  int npix = NB*H*H;
  if(pix >= npix) return;
  int b = pix/(H*H);
  const bf16* ap = act + ((size_t)pix << 9);
  const float* sp = sT + ((size_t)lt*NB + b)*512;
  const float* w0 = tw + ((size_t)lt*3 + 0)*512;
  const float* w1 = tw + ((size_t)lt*3 + 1)*512;
  const float* w2 = tw + ((size_t)lt*3 + 2)*512;
  float a0 = 0.f, a1 = 0.f, a2 = 0.f;
  #pragma unroll
  for(int j = 0; j < 8; j++){
    int i = lane + j*64;
    float xs = __bfloat162float(ap[i])*sp[i];
    a0 += xs*w0[i]; a1 += xs*w1[i]; a2 += xs*w2[i];
  }
  for(int off = 32; off > 0; off >>= 1){
    a0 += __shfl_xor(a0, off);
    a1 += __shfl_xor(a1, off);
    a2 += __shfl_xor(a2, off);
  }
  if(lane == 0){
    int rem = pix % (H*H);
    size_t o0 = ((size_t)(b*3 + 0)*H*H) + rem;
    size_t o1 = ((size_t)(b*3 + 1)*H*H) + rem;
    size_t o2 = ((size_t)(b*3 + 2)*H*H) + rem;
    float b0 = tbias[lt*3+0], b1 = tbias[lt*3+1], b2 = tbias[lt*3+2];
    if(addflag){ dst[o0] += a0 + b0; dst[o1] += a1 + b1; dst[o2] += a2 + b2; }
    else       { dst[o0]  = a0 + b0; dst[o1]  = a1 + b1; dst[o2]  = a2 + b2; }
  }
}

// ---------------- skip upsample 2x (NCHW, 3ch) -------------------------------
__global__ void k_skipup(const float* __restrict__ sin, float* __restrict__ sout, int h){
  const int O = 2*h;
  int gid = blockIdx.x*256 + threadIdx.x;
  int total = NB*3*O*O;
  if(gid >= total) return;
  int X = gid % O; int Y = (gid/O) % O; int c = (gid/(O*O)) % 3; int b = gid/(3*O*O);
  const float k1[4] = {1.f, 3.f, 3.f, 1.f};
  float acc = 0.f;
  for(int ky = (Y & 1); ky < 4; ky += 2){
    int ty = Y + ky - 2;
    if(ty < 0) continue;
    int y = ty >> 1; if(y >= h) continue;
    for(int kx = (X & 1); kx < 4; kx += 2){
      int tx = X + kx - 2;
      if(tx < 0) continue;
      int x = tx >> 1; if(x >= h) continue;
      acc += k1[ky]*k1[kx]*(1.f/16.f) * sin[((size_t)(b*3 + c)*h + y)*h + x];
    }
  }
  sout[gid] = acc;
}

// ---------------------------------------------------------------------------
extern "C" void kernel_launch(void* const* d_in, const int* in_sizes, int n_in,
                              void* d_out, int out_size, void* d_ws, size_t ws_size,
                              hipStream_t stream){
  const float* z     = (const float*)d_in[0];
  const float* mlp_w = (const float*)d_in[1];
  const float* mlp_b = (const float*)d_in[2];
  const float* cinp  = (const float*)d_in[3];
  const float* conv_w= (const float*)d_in[4];
  const float* csw   = (const float*)d_in[5];
  const float* csb   = (const float*)d_in[6];
  const float* nwp   = (const float*)d_in[7];
  const float* abp   = (const float*)d_in[8];
  const float* tw    = (const float*)d_in[9];
  const float* tsw   = (const float*)d_in[10];
  const float* tsb   = (const float*)d_in[11];
  const float* tb    = (const float*)d_in[12];
  const float* noise[9];
  for(int i = 0; i < 9; i++) noise[i] = (const float*)d_in[13 + i];

  // workspace layout (bytes)
  const size_t UMAX = (size_t)32*65*65*512;       // 69,206,016 elems
  char* base = (char*)d_ws;
  size_t off = 0;
  bf16* buf0 = (bf16*)(base + off); off += UMAX*2;                 // 138,412,032
  bf16* buf1 = (bf16*)(base + off); off += UMAX*2;                 // 138,412,032
  bf16* wT   = (bf16*)(base + off); off += (size_t)9*9*512*512*2;  //  42,467,328
  float* wsq = (float*)(base + off); off += (size_t)9*512*512*4;   //   9,437,184
  float* wlat= (float*)(base + off); off += (size_t)32*512*4;
  float* sconv=(float*)(base + off); off += (size_t)9*32*512*4;
  float* dconv=(float*)(base + off); off += (size_t)9*32*512*4;
  float* strgb=(float*)(base + off); off += (size_t)5*32*512*4;
  float* skipA=(float*)(base + off); off += (size_t)32*3*64*64*4;
  float* skipB=(float*)(base + off); off += (size_t)32*3*64*64*4;
  if(ws_size < off){
    fprintf(stderr, "kernel_launch: ws too small (%zu < %zu)\n", ws_size, off);
    return;
  }
  float* out = (float*)d_out;

  // prep
  k_mapping<<<32, 256, 0, stream>>>(z, mlp_w, mlp_b, wlat);
  k_styles <<<896, 256, 0, stream>>>(wlat, csw, csb, tsw, tsb, sconv, strgb);
  k_wsq    <<<9216, 256, 0, stream>>>(conv_w, wsq);
  k_demod  <<<288, 256, 0, stream>>>(sconv, wsq, dconv);
  k_wT     <<<dim3(16,16,9), 256, 0, stream>>>(conv_w, wT);
  k_init   <<<1024, 256, 0, stream>>>(cinp, buf0);

  auto conv_noup = [&](const bf16* in, bf16* o, int H, int layer){
    int M = 32*H*H; dim3 g((M + 127)/128, 4);
    k_conv<false,true><<<g, 256, 0, stream>>>(in, wT, sconv, dconv, noise[layer], nwp, abp, o, H, layer);
  };
  auto conv_up = [&](const bf16* in, bf16* o, int Hin, int layer){
    int OHp = 2*Hin + 1; int M = 32*OHp*OHp; dim3 g((M + 127)/128, 4);
    k_conv<true,false><<<g, 256, 0, stream>>>(in, wT, sconv, dconv, noise[layer], nwp, abp, o, Hin, layer);
  };
  auto blur = [&](const bf16* u, bf16* o, int O, int layer){
    size_t total = (size_t)32*O*O*128;
    k_blur<<<(unsigned)((total + 255)/256), 256, 0, stream>>>(u, noise[layer], nwp, abp, o, O, layer);
  };
  auto torgb = [&](const bf16* act, float* dst, int H, int lt, int add){
    int npix = 32*H*H;
    k_torgb<<<(npix + 3)/4, 256, 0, stream>>>(act, tw, strgb, tb, dst, H, lt, add);
  };
  auto skipup = [&](const float* sin, float* sout, int h){
    int total = 32*3*(2*h)*(2*h);
    k_skipup<<<(total + 255)/256, 256, 0, stream>>>(sin, sout, h);
  };

  // layer 0 @4
  conv_noup(buf0, buf1, 4, 0);              // act -> buf1
  torgb(buf1, skipA, 4, 0, 0);              // skip @4

  // r=0: 4->8
  conv_up(buf1, buf0, 4, 1);                // u(9^2) -> buf0
  blur(buf0, buf1, 8, 1);                   // act @8 -> buf1
  conv_noup(buf1, buf0, 8, 2);              // act @8 -> buf0
  skipup(skipA, skipB, 4);
  torgb(buf0, skipB, 8, 1, 1);

  // r=1: 8->16
  conv_up(buf0, buf1, 8, 3);
  blur(buf1, buf0, 16, 3);
  conv_noup(buf0, buf1, 16, 4);
  skipup(skipB, skipA, 8);
  torgb(buf1, skipA, 16, 2, 1);

  // r=2: 16->32
  conv_up(buf1, buf0, 16, 5);
  blur(buf0, buf1, 32, 5);
  conv_noup(buf1, buf0, 32, 6);
  skipup(skipA, skipB, 16);
  torgb(buf0, skipB, 32, 3, 1);

  // r=3: 32->64
  conv_up(buf0, buf1, 32, 7);               // u(65^2) -> buf1
  blur(buf1, buf0, 64, 7);                  // act @64 -> buf0
  conv_noup(buf0, buf1, 64, 8);             // act @64 -> buf1
  skipup(skipB, out, 32);                   // overwrite d_out (poison-safe)
  torgb(buf1, out, 64, 4, 1);               // final skip add -> d_out
}

// Round 3
// 3829.512 us; speedup vs baseline: 6.5809x; 6.5809x over previous
//
#include <hip/hip_runtime.h>
#include <hip/hip_bf16.h>
#include <cstdio>
#include <math.h>

// ---------------------------------------------------------------------------
// StyleGANv2 generator forward. bf16 MFMA implicit-GEMM convolutions.
//
//   mod+demod conv == d[b,o] * conv(x * s'[b,i], w_shared)
//   Scale-folding: every activation tensor is stored PRE-SCALED by the
//   consuming conv layer's s' (applied in the producer epilogue), so the
//   GEMM A-operand is a pure bf16 gather. toRGB compensates via
//   rat[lt][b][i] = s_trgb/s_consumer (bf16 rel-error is scale-invariant).
//   Up-conv (convT stride2 k3) = parity-predicate gather over 9 taps.
//   Activations channel-last (B,H,W,C=512), weights wB[l][tap][o][i] bf16.
// ---------------------------------------------------------------------------

static constexpr int NB = 32;
static constexpr float SQRT2F      = 1.41421356237309515f;
static constexpr float INV_SQRT512 = 0.04419417382415922f;   // 1/sqrt(512)
static constexpr float INV_SQRT4608= 0.014731391274719742f;  // 1/sqrt(512*9)

typedef __hip_bfloat16 bf16;
typedef __attribute__((ext_vector_type(8))) short bf16x8;
typedef __attribute__((ext_vector_type(4))) float f32x4;

__device__ __forceinline__ float lrelu_s2(float v){ return (v > 0.f ? v : 0.2f*v) * SQRT2F; }
__device__ __forceinline__ float bf_lo(unsigned u){ unsigned v = u << 16; return __builtin_bit_cast(float, v); }
__device__ __forceinline__ float bf_hi(unsigned u){ unsigned v = u & 0xffff0000u; return __builtin_bit_cast(float, v); }
__device__ __forceinline__ unsigned packbf2(float a, float b){
  bf16 ha = __float2bfloat16(a), hb = __float2bfloat16(b);
  unsigned short ra = __builtin_bit_cast(unsigned short, ha);
  unsigned short rb = __builtin_bit_cast(unsigned short, hb);
  return (unsigned)ra | ((unsigned)rb << 16);
}

// ---------------- mapping network: pixel_norm + 8x (512x512 lrelu) ----------
__global__ void k_mapping(const float* __restrict__ z, const float* __restrict__ mlp_w,
                          const float* __restrict__ mlp_b, float* __restrict__ wlat){
  __shared__ float xb[512], yb[512], red[256];
  int b = blockIdx.x, t = threadIdx.x;
  float z0 = z[b*512 + t], z1 = z[b*512 + t + 256];
  red[t] = z0*z0 + z1*z1;
  __syncthreads();
  for(int s = 128; s > 0; s >>= 1){ if(t < s) red[t] += red[t+s]; __syncthreads(); }
  float norm = sqrtf(red[0]) * INV_SQRT512;
  float inv = 1.f / (norm + 1e-6f);
  xb[t] = z0*inv; xb[t+256] = z1*inv;
  __syncthreads();
  for(int l = 0; l < 8; l++){
    const float* Wl = mlp_w + (size_t)l*512*512;
    const float* bl = mlp_b + l*512;
    for(int oo = 0; oo < 2; oo++){
      int o = t + oo*256;
      const float4* wr = (const float4*)(Wl + (size_t)o*512);
      float acc = 0.f;
      #pragma unroll 4
      for(int k = 0; k < 128; k++){
        float4 w4 = wr[k];
        acc += w4.x*xb[4*k] + w4.y*xb[4*k+1] + w4.z*xb[4*k+2] + w4.w*xb[4*k+3];
      }
      yb[o] = lrelu_s2(acc*INV_SQRT512 + bl[o]*0.01f);
    }
    __syncthreads();
    xb[t] = yb[t]; xb[t+256] = yb[t+256];
    __syncthreads();
  }
  wlat[b*512+t] = xb[t]; wlat[b*512+t+256] = xb[t+256];
}

// ---------------- styles: s' for 9 conv layers + 5 torgb layers -------------
__global__ void k_styles(const float* __restrict__ wlat,
                         const float* __restrict__ csw, const float* __restrict__ csb,
                         const float* __restrict__ tsw, const float* __restrict__ tsb,
                         float* __restrict__ s_conv, float* __restrict__ s_trgb){
  int gid = blockIdx.x*256 + threadIdx.x;        // 14*32*512 = 229376 exactly
  int l = gid >> 14;
  int b = (gid >> 9) & 31;
  int i = gid & 511;
  const float* row; float bias, wsc;
  if(l < 9){ row = csw + ((size_t)l*512 + i)*512; bias = csb[l*512+i]; wsc = INV_SQRT4608; }
  else     { int lt = l-9; row = tsw + ((size_t)lt*512 + i)*512; bias = tsb[lt*512+i]; wsc = INV_SQRT512; }
  const float4* r4 = (const float4*)row;
  const float4* w4 = (const float4*)(wlat + b*512);
  float acc = 0.f;
  #pragma unroll 4
  for(int k = 0; k < 128; k++){
    float4 a = w4[k], c = r4[k];
    acc += a.x*c.x + a.y*c.y + a.z*c.z + a.w*c.w;
  }
  float s = (acc*INV_SQRT512 + bias) * wsc;
  if(l < 9) s_conv[((size_t)l*32 + b)*512 + i] = s;
  else      s_trgb[((size_t)(l-9)*32 + b)*512 + i] = s;
}

// ---------------- wsq[l,o,i] = sum over 9 taps of w^2 -----------------------
__global__ void k_wsq(const float* __restrict__ cw, float* __restrict__ wsq){
  int gid = blockIdx.x*256 + threadIdx.x;        // 9*512*512
  const float* p = cw + (size_t)gid*9;
  float a = 0.f;
  #pragma unroll
  for(int t = 0; t < 9; t++){ float v = p[t]; a += v*v; }
  wsq[gid] = a;
}

// ---------------- demod d[l,b,o] ---------------------------------------------
__global__ void k_demod(const float* __restrict__ s_conv, const float* __restrict__ wsq,
                        float* __restrict__ d_conv){
  __shared__ float s2[512];
  int l = blockIdx.x/32, b = blockIdx.x%32, t = threadIdx.x;
  size_t base = ((size_t)l*32 + b)*512;
  float v0 = s_conv[base + t], v1 = s_conv[base + t + 256];
  s2[t] = v0*v0; s2[t+256] = v1*v1;
  __syncthreads();
  for(int oo = 0; oo < 2; oo++){
    int o = t + oo*256;
    const float4* wr = (const float4*)(wsq + ((size_t)l*512 + o)*512);
    float acc = 0.f;
    #pragma unroll 4
    for(int k = 0; k < 128; k++){
      float4 w = wr[k];
      acc += w.x*s2[4*k] + w.y*s2[4*k+1] + w.z*s2[4*k+2] + w.w*s2[4*k+3];
    }
    d_conv[base + o] = rsqrtf(acc + 1e-8f);
  }
}

// ---------------- torgb compensation ratio ----------------------------------
// rat[lt][b][i] = s_trgb[lt][b][i] / s_conv[consumer(lt)][b][i]; lt=4 -> 1
__global__ void k_ratio(const float* __restrict__ s_conv, const float* __restrict__ s_trgb,
                        float* __restrict__ rat){
  int gid = blockIdx.x*256 + threadIdx.x;        // 5*32*512 = 81920
  int lt = gid >> 14;
  if(lt >= 4){ rat[gid] = 1.0f; return; }
  int b = (gid >> 9) & 31;
  int i = gid & 511;
  int cl = 1 + 2*lt;                             // consuming conv layer
  float st = s_trgb[((size_t)lt*32 + b)*512 + i];
  float sc = s_conv[((size_t)cl*32 + b)*512 + i];
  rat[gid] = (sc != 0.f) ? st/sc : 0.f;
}

// ---------------- weights: wB[l][tap][o][i] bf16 from cw[l][o][i][tap] -------
__global__ void k_wB(const float* __restrict__ cw, bf16* __restrict__ wB){
  int gid = blockIdx.x*256 + threadIdx.x;        // 9*512*512; (l,o,i)
  const float* p = cw + (size_t)gid*9;
  int l = gid >> 18;
  int oi = gid & 0x3ffff;                        // o*512 + i
  #pragma unroll
  for(int tap = 0; tap < 9; tap++)
    wB[((size_t)(l*9 + tap) << 18) + oi] = __float2bfloat16(p[tap]);
}

// ---------------- const input -> act0 (B,4,4,512) pre-scaled by s_conv[0] ----
__global__ void k_init(const float* __restrict__ ci, const float* __restrict__ s_conv,
                       bf16* __restrict__ act){
  int gid = blockIdx.x*256 + threadIdx.x;        // 32*16*512 = 262144
  int c = gid & 511; int px = (gid >> 9) & 15; int b = gid >> 13;
  act[gid] = __float2bfloat16(ci[c*16 + px] * s_conv[b*512 + c]);
}

// ---------------- main conv: MFMA implicit GEMM, 128x128 tile, 4 waves -------
// A = pre-scaled act (bf16 gather with tap/parity predicates), B = wB bf16.
// UP=false,EPI=true : out = lrelu(acc*d + noise + bias)*sqrt2 * sN  (bf16)
// UP=true ,EPI=false: out = acc*d (bf16), blur applies the rest.
template<bool UP, bool EPI>
__global__ __launch_bounds__(256)
void k_conv(const bf16* __restrict__ act, const bf16* __restrict__ wL,
            const float* __restrict__ dL, const float* __restrict__ noise,
            const float* __restrict__ nw_ptr, const float* __restrict__ ab,
            const float* __restrict__ sN, bf16* __restrict__ outp, int Hin){
  const int OH = UP ? (2*Hin + 1) : Hin;
  const int OHOH = OH*OH;
  const int Mtot = NB*OHOH;
  __shared__ short As[128*40];                   // padded rows: 40 elems = 80 B
  __shared__ short Bs[128*40];
  const int t = threadIdx.x;
  const int mbase = blockIdx.x*128;
  const int nbase = blockIdx.y*128;

  // staging assignment: units (row, slot) with row 0..127, slot 0..3 (8 ch each)
  const int slot = t & 3;
  const int rowq0 = t >> 2, rowq1 = (t >> 2) + 64;
  int rowq[2] = {rowq0, rowq1};
  int gb[2], gY[2], gX[2]; bool mval[2];
  #pragma unroll
  for(int q = 0; q < 2; q++){
    int m = mbase + rowq[q];
    mval[q] = (m < Mtot);
    int mm = mval[q] ? m : 0;
    gb[q] = mm / OHOH; int rem = mm % OHOH; gY[q] = rem / OH; gX[q] = rem % OH;
  }

  // MFMA fragment geometry (wave = 64 lanes; 4 waves in 2x2 over 128x128)
  const int wid = t >> 6;
  const int mrow0 = (wid >> 1)*64;               // wave M offset
  const int ncol0 = (wid & 1)*64;                // wave N offset
  const int lr = t & 15;                         // frag row/col lane index
  const int ks = (t & 63) >> 4;                  // k-slot (8 bf16 each)

  f32x4 acc[4][4];
  #pragma unroll
  for(int i = 0; i < 4; i++)
    #pragma unroll
    for(int j = 0; j < 4; j++) acc[i][j] = (f32x4){0.f,0.f,0.f,0.f};

  for(int tap = 0; tap < 9; tap++){
    const int dy = tap/3, dx = tap%3;
    const bf16* aptr[2]; bool ok[2];
    #pragma unroll
    for(int q = 0; q < 2; q++){
      ok[q] = false; aptr[q] = act;
      if(mval[q]){
        int yy, xx; bool o;
        if(UP){
          int ty = gY[q] - dy, tx = gX[q] - dx;
          o = (ty >= 0) && (tx >= 0) && !(ty & 1) && !(tx & 1);
          yy = ty >> 1; xx = tx >> 1;
          o = o && (yy < Hin) && (xx < Hin);
        } else {
          yy = gY[q] + dy - 1; xx = gX[q] + dx - 1;
          o = (yy >= 0) && (yy < Hin) && (xx >= 0) && (xx < Hin);
        }
        if(o){ ok[q] = true; aptr[q] = act + ((size_t)((gb[q]*Hin + yy)*Hin + xx) << 9) + slot*8; }
      }
    }
    const bf16* bptr[2];
    #pragma unroll
    for(int q = 0; q < 2; q++)
      bptr[q] = wL + (((size_t)tap*512 + nbase + rowq[q]) << 9) + slot*8;

    for(int icc = 0; icc < 512; icc += 32){
      __syncthreads();
      #pragma unroll
      for(int q = 0; q < 2; q++){
        uint4 av = make_uint4(0u,0u,0u,0u);
        if(ok[q]) av = *(const uint4*)(aptr[q] + icc);
        *(uint4*)&As[rowq[q]*40 + slot*8] = av;
        uint4 bv = *(const uint4*)(bptr[q] + icc);
        *(uint4*)&Bs[rowq[q]*40 + slot*8] = bv;
      }
      __syncthreads();
      bf16x8 af[4], bfr[4];
      #pragma unroll
      for(int f = 0; f < 4; f++){
        af[f]  = *(const bf16x8*)&As[(mrow0 + f*16 + lr)*40 + ks*8];
        bfr[f] = *(const bf16x8*)&Bs[(ncol0 + f*16 + lr)*40 + ks*8];
      }
      #pragma unroll
      for(int mf = 0; mf < 4; mf++)
        #pragma unroll
        for(int nf = 0; nf < 4; nf++)
          acc[mf][nf] = __builtin_amdgcn_mfma_f32_16x16x32_bf16(af[mf], bfr[nf], acc[mf][nf], 0, 0, 0);
    }
  }

  // epilogue: C/D frag mapping col=lane&15, row=(lane>>4)*4+reg  [m89-verified]
  const float nwv = EPI ? *nw_ptr : 0.f;
  #pragma unroll
  for(int mf = 0; mf < 4; mf++){
    #pragma unroll
    for(int r = 0; r < 4; r++){
      int m = mbase + mrow0 + mf*16 + ks*4 + r;
      if(m >= Mtot) continue;
      int b = m / OHOH; int rem = m % OHOH; int Y = rem / OH, X = rem % OH;
      float nz = EPI ? nwv * noise[(b*OH + Y)*OH + X] : 0.f;
      const float* drow = dL + b*512;
      const float* srow = EPI ? (sN + b*512) : nullptr;
      bf16* orow = outp + ((size_t)m << 9);
      #pragma unroll
      for(int nf = 0; nf < 4; nf++){
        int n = nbase + ncol0 + nf*16 + lr;
        float val = acc[mf][nf][r] * drow[n];
        if(EPI) val = lrelu_s2(val + nz + ab[n]) * srow[n];
        orow[n] = __float2bfloat16(val);
      }
    }
  }
}

// ---------------- 4x4 blur + noise + bias + act + next-scale -----------------
__global__ void k_blur(const bf16* __restrict__ u, const float* __restrict__ noise,
                       const float* __restrict__ nw_ptr, const float* __restrict__ ab,
                       const float* __restrict__ sN, bf16* __restrict__ act, int O){
  const int U = O + 1;
  size_t gid = (size_t)blockIdx.x*256 + threadIdx.x;
  size_t total = (size_t)NB*O*O*128;
  if(gid >= total) return;
  int c4 = gid & 127;
  size_t pix = gid >> 7;
  int X = pix % O; int Y = (pix/O) % O; int b = pix/((size_t)O*O);
  const float k1[4] = {1.f, 3.f, 3.f, 1.f};
  float4 a = make_float4(0.f,0.f,0.f,0.f);
  #pragma unroll
  for(int ky = 0; ky < 4; ky++){
    int yy = Y + ky - 1; if(yy < 0 || yy >= U) continue;
    #pragma unroll
    for(int kx = 0; kx < 4; kx++){
      int xx = X + kx - 1; if(xx < 0 || xx >= U) continue;
      float w = k1[ky]*k1[kx]*(1.f/16.f);
      uint2 u2 = *(const uint2*)(u + (((size_t)(b*U + yy)*U + xx) << 9) + c4*4);
      a.x += w*bf_lo(u2.x); a.y += w*bf_hi(u2.x);
      a.z += w*bf_lo(u2.y); a.w += w*bf_hi(u2.y);
    }
  }
  float nz = (*nw_ptr) * noise[(b*O + Y)*O + X];
  const float* abp4 = ab + c4*4;
  float4 s4 = *(const float4*)(sN + b*512 + c4*4);
  uint2 pk;
  pk.x = packbf2(lrelu_s2(a.x + nz + abp4[0])*s4.x, lrelu_s2(a.y + nz + abp4[1])*s4.y);
  pk.y = packbf2(lrelu_s2(a.z + nz + abp4[2])*s4.z, lrelu_s2(a.w + nz + abp4[3])*s4.w);
  *(uint2*)(act + (pix << 9) + c4*4) = pk;
}

// ---------------- toRGB (1x1 mod conv, no demod) -> NCHW skip ----------------
// act is pre-scaled by the conv consumer's s; rat row compensates to s_trgb.
__global__ void k_torgb(const bf16* __restrict__ act, const float* __restrict__ tw,
                        const float* __restrict__ ratL, const float* __restrict__ tbias,
                        float* __restrict__ dst, int H, int lt, int addflag){
  int wid = threadIdx.x >> 6, lane = threadIdx.x & 63;
  int pix = blockIdx.x*4 + wid;
  int npix = NB*H*H;
  if(pix >= npix) return;
  int b = pix/(H*H);
  const bf16* ap = act + ((size_t)pix << 9);
  const float* rp = ratL + (size_t)b*512;
  const float* w0 = tw + ((size_t)lt*3 + 0)*512;
  const float* w1 = tw + ((size_t)lt*3 + 1)*512;
  const float* w2 = tw + ((size_t)lt*3 + 2)*512;
  float a0 = 0.f, a1 = 0.f, a2 = 0.f;
  #pragma unroll
  for(int j = 0; j < 8; j++){
    int i = lane + j*64;
    float xs = __bfloat162float(ap[i])*rp[i];
    a0 += xs*w0[i]; a1 += xs*w1[i]; a2 += xs*w2[i];
  }
  for(int off = 32; off > 0; off >>= 1){
    a0 += __shfl_xor(a0, off);
    a1 += __shfl_xor(a1, off);
    a2 += __shfl_xor(a2, off);
  }
  if(lane == 0){
    int rem = pix % (H*H);
    size_t o0 = ((size_t)(b*3 + 0)*H*H) + rem;
    size_t o1 = ((size_t)(b*3 + 1)*H*H) + rem;
    size_t o2 = ((size_t)(b*3 + 2)*H*H) + rem;
    float b0 = tbias[lt*3+0], b1 = tbias[lt*3+1], b2 = tbias[lt*3+2];
    if(addflag){ dst[o0] += a0 + b0; dst[o1] += a1 + b1; dst[o2] += a2 + b2; }
    else       { dst[o0]  = a0 + b0; dst[o1]  = a1 + b1; dst[o2]  = a2 + b2; }
  }
}

// ---------------- skip upsample 2x (NCHW, 3ch) -------------------------------
__global__ void k_skipup(const float* __restrict__ sin, float* __restrict__ sout, int h){
  const int O = 2*h;
  int gid = blockIdx.x*256 + threadIdx.x;
  int total = NB*3*O*O;
  if(gid >= total) return;
  int X = gid % O; int Y = (gid/O) % O; int c = (gid/(O*O)) % 3; int b = gid/(3*O*O);
  const float k1[4] = {1.f, 3.f, 3.f, 1.f};
  float acc = 0.f;
  for(int ky = (Y & 1); ky < 4; ky += 2){
    int ty = Y + ky - 2;
    if(ty < 0) continue;
    int y = ty >> 1; if(y >= h) continue;
    for(int kx = (X & 1); kx < 4; kx += 2){
      int tx = X + kx - 2;
      if(tx < 0) continue;
      int x = tx >> 1; if(x >= h) continue;
      acc += k1[ky]*k1[kx]*(1.f/16.f) * sin[((size_t)(b*3 + c)*h + y)*h + x];
    }
  }
  sout[gid] = acc;
}

// ---------------------------------------------------------------------------
extern "C" void kernel_launch(void* const* d_in, const int* in_sizes, int n_in,
                              void* d_out, int out_size, void* d_ws, size_t ws_size,
                              hipStream_t stream){
  const float* z     = (const float*)d_in[0];
  const float* mlp_w = (const float*)d_in[1];
  const float* mlp_b = (const float*)d_in[2];
  const float* cinp  = (const float*)d_in[3];
  const float* conv_w= (const float*)d_in[4];
  const float* csw   = (const float*)d_in[5];
  const float* csb   = (const float*)d_in[6];
  const float* nwp   = (const float*)d_in[7];
  const float* abp   = (const float*)d_in[8];
  const float* tw    = (const float*)d_in[9];
  const float* tsw   = (const float*)d_in[10];
  const float* tsb   = (const float*)d_in[11];
  const float* tb    = (const float*)d_in[12];
  const float* noise[9];
  for(int i = 0; i < 9; i++) noise[i] = (const float*)d_in[13 + i];

  // workspace layout (bytes)
  const size_t UMAX = (size_t)32*65*65*512;       // 69,206,016 elems
  char* base = (char*)d_ws;
  size_t off = 0;
  bf16* buf0 = (bf16*)(base + off); off += UMAX*2;                 // 138,412,032
  bf16* buf1 = (bf16*)(base + off); off += UMAX*2;                 // 138,412,032
  bf16* wB   = (bf16*)(base + off); off += (size_t)9*9*512*512*2;  //  42,467,328
  float* wsq = (float*)(base + off); off += (size_t)9*512*512*4;   //   9,437,184
  float* wlat= (float*)(base + off); off += (size_t)32*512*4;
  float* sconv=(float*)(base + off); off += (size_t)9*32*512*4;
  float* dconv=(float*)(base + off); off += (size_t)9*32*512*4;
  float* strgb=(float*)(base + off); off += (size_t)5*32*512*4;
  float* rat  =(float*)(base + off); off += (size_t)5*32*512*4;
  float* skipA=(float*)(base + off); off += (size_t)32*3*64*64*4;
  float* skipB=(float*)(base + off); off += (size_t)32*3*64*64*4;
  if(ws_size < off){
    fprintf(stderr, "kernel_launch: ws too small (%zu < %zu)\n", ws_size, off);
    return;
  }
  float* out = (float*)d_out;

  // prep
  k_mapping<<<32, 256, 0, stream>>>(z, mlp_w, mlp_b, wlat);
  k_styles <<<896, 256, 0, stream>>>(wlat, csw, csb, tsw, tsb, sconv, strgb);
  k_wsq    <<<9216, 256, 0, stream>>>(conv_w, wsq);
  k_demod  <<<288, 256, 0, stream>>>(sconv, wsq, dconv);
  k_ratio  <<<320, 256, 0, stream>>>(sconv, strgb, rat);
  k_wB     <<<9216, 256, 0, stream>>>(conv_w, wB);
  k_init   <<<1024, 256, 0, stream>>>(cinp, sconv, buf0);

  auto conv_noup = [&](const bf16* in, bf16* o, int H, int layer, const float* sN){
    int M = 32*H*H; dim3 g((M + 127)/128, 4);
    k_conv<false,true><<<g, 256, 0, stream>>>(in, wB + ((size_t)layer*9 << 18),
        dconv + (size_t)layer*NB*512, noise[layer], nwp + layer, abp + layer*512, sN, o, H);
  };
  auto conv_up = [&](const bf16* in, bf16* o, int Hin, int layer){
    int OHp = 2*Hin + 1; int M = 32*OHp*OHp; dim3 g((M + 127)/128, 4);
    k_conv<true,false><<<g, 256, 0, stream>>>(in, wB + ((size_t)layer*9 << 18),
        dconv + (size_t)layer*NB*512, nullptr, nullptr, nullptr, nullptr, o, Hin);
  };
  auto blur = [&](const bf16* u, bf16* o, int O, int layer, const float* sN){
    size_t total = (size_t)32*O*O*128;
    k_blur<<<(unsigned)((total + 255)/256), 256, 0, stream>>>(u, noise[layer], nwp + layer,
        abp + layer*512, sN, o, O);
  };
  auto torgb = [&](const bf16* act, float* dst, int H, int lt, int add){
    int npix = 32*H*H;
    k_torgb<<<(npix + 3)/4, 256, 0, stream>>>(act, tw, rat + (size_t)lt*NB*512, tb, dst, H, lt, add);
  };
  auto skipup = [&](const float* sin, float* sout, int h){
    int total = 32*3*(2*h)*(2*h);
    k_skipup<<<(total + 255)/256, 256, 0, stream>>>(sin, sout, h);
  };

  const float* S = sconv;   // s rows per layer: S + layer*NB*512
  const float* sT4 = strgb + (size_t)4*NB*512;

  // layer 0 @4   (output scaled by s1)
  conv_noup(buf0, buf1, 4, 0, S + (size_t)1*NB*512);
  torgb(buf1, skipA, 4, 0, 0);

  // r=0: 4->8
  conv_up(buf1, buf0, 4, 1);
  blur(buf0, buf1, 8, 1, S + (size_t)2*NB*512);
  conv_noup(buf1, buf0, 8, 2, S + (size_t)3*NB*512);
  skipup(skipA, skipB, 4);
  torgb(buf0, skipB, 8, 1, 1);

  // r=1: 8->16
  conv_up(buf0, buf1, 8, 3);
  blur(buf1, buf0, 16, 3, S + (size_t)4*NB*512);
  conv_noup(buf0, buf1, 16, 4, S + (size_t)5*NB*512);
  skipup(skipB, skipA, 8);
  torgb(buf1, skipA, 16, 2, 1);

  // r=2: 16->32
  conv_up(buf1, buf0, 16, 5);
  blur(buf0, buf1, 32, 5, S + (size_t)6*NB*512);
  conv_noup(buf1, buf0, 32, 6, S + (size_t)7*NB*512);
  skipup(skipA, skipB, 16);
  torgb(buf0, skipB, 32, 3, 1);

  // r=3: 32->64
  conv_up(buf0, buf1, 32, 7);
  blur(buf1, buf0, 64, 7, S + (size_t)8*NB*512);
  conv_noup(buf0, buf1, 64, 8, sT4);            // last conv: scale by s_trgb4
  skipup(skipB, out, 32);                        // overwrite d_out (poison-safe)
  torgb(buf1, out, 64, 4, 1);                    // final skip add -> d_out
}

// Round 4
// 2528.059 us; speedup vs baseline: 9.9687x; 1.5148x over previous
//
#include <hip/hip_runtime.h>
#include <hip/hip_bf16.h>
#include <cstdio>
#include <math.h>

// ---------------------------------------------------------------------------
// StyleGANv2 generator forward. bf16 MFMA implicit-GEMM convolutions.
//   mod+demod conv == d[b,o] * conv(x * s'[b,i], w_shared); s' folded into the
//   producer epilogue so GEMM A-operand is a pure bf16 gather.
//   Up-conv (convT stride2 k3): parity-decomposed — blockIdx.z = output parity
//   class (py,px); valid taps per class: (0,0):4 (0,1):2 (1,0):2 (1,1):1.
//   k_conv: 128x128 tile, K-step 64 (2x32 halves), reg-prefetch + raw s_barrier
//   pipeline (prefetch loads stay in flight across barriers), n-inner 1D grid
//   with bijective XCD swizzle for A-tile L2 reuse.
// ---------------------------------------------------------------------------

static constexpr int NB = 32;
static constexpr float SQRT2F      = 1.41421356237309515f;
static constexpr float INV_SQRT512 = 0.04419417382415922f;   // 1/sqrt(512)
static constexpr float INV_SQRT4608= 0.014731391274719742f;  // 1/sqrt(512*9)

typedef __hip_bfloat16 bf16;
typedef __attribute__((ext_vector_type(8))) short bf16x8;
typedef __attribute__((ext_vector_type(4))) float f32x4;

__device__ __forceinline__ float lrelu_s2(float v){ return (v > 0.f ? v : 0.2f*v) * SQRT2F; }
__device__ __forceinline__ float bf_lo(unsigned u){ unsigned v = u << 16; return __builtin_bit_cast(float, v); }
__device__ __forceinline__ float bf_hi(unsigned u){ unsigned v = u & 0xffff0000u; return __builtin_bit_cast(float, v); }
__device__ __forceinline__ unsigned packbf2(float a, float b){
  bf16 ha = __float2bfloat16(a), hb = __float2bfloat16(b);
  unsigned short ra = __builtin_bit_cast(unsigned short, ha);
  unsigned short rb = __builtin_bit_cast(unsigned short, hb);
  return (unsigned)ra | ((unsigned)rb << 16);
}

// ---------------- mapping network: pixel_norm + 8x (512x512 lrelu) ----------
__global__ void k_mapping(const float* __restrict__ z, const float* __restrict__ mlp_w,
                          const float* __restrict__ mlp_b, float* __restrict__ wlat){
  __shared__ float xb[512], yb[512], red[256];
  int b = blockIdx.x, t = threadIdx.x;
  float z0 = z[b*512 + t], z1 = z[b*512 + t + 256];
  red[t] = z0*z0 + z1*z1;
  __syncthreads();
  for(int s = 128; s > 0; s >>= 1){ if(t < s) red[t] += red[t+s]; __syncthreads(); }
  float norm = sqrtf(red[0]) * INV_SQRT512;
  float inv = 1.f / (norm + 1e-6f);
  xb[t] = z0*inv; xb[t+256] = z1*inv;
  __syncthreads();
  for(int l = 0; l < 8; l++){
    const float* Wl = mlp_w + (size_t)l*512*512;
    const float* bl = mlp_b + l*512;
    for(int oo = 0; oo < 2; oo++){
      int o = t + oo*256;
      const float4* wr = (const float4*)(Wl + (size_t)o*512);
      float acc = 0.f;
      #pragma unroll 4
      for(int k = 0; k < 128; k++){
        float4 w4 = wr[k];
        acc += w4.x*xb[4*k] + w4.y*xb[4*k+1] + w4.z*xb[4*k+2] + w4.w*xb[4*k+3];
      }
      yb[o] = lrelu_s2(acc*INV_SQRT512 + bl[o]*0.01f);
    }
    __syncthreads();
    xb[t] = yb[t]; xb[t+256] = yb[t+256];
    __syncthreads();
  }
  wlat[b*512+t] = xb[t]; wlat[b*512+t+256] = xb[t+256];
}

// ---------------- styles: s' for 9 conv layers + 5 torgb layers -------------
__global__ void k_styles(const float* __restrict__ wlat,
                         const float* __restrict__ csw, const float* __restrict__ csb,
                         const float* __restrict__ tsw, const float* __restrict__ tsb,
                         float* __restrict__ s_conv, float* __restrict__ s_trgb){
  int gid = blockIdx.x*256 + threadIdx.x;        // 14*32*512 = 229376 exactly
  int l = gid >> 14;
  int b = (gid >> 9) & 31;
  int i = gid & 511;
  const float* row; float bias, wsc;
  if(l < 9){ row = csw + ((size_t)l*512 + i)*512; bias = csb[l*512+i]; wsc = INV_SQRT4608; }
  else     { int lt = l-9; row = tsw + ((size_t)lt*512 + i)*512; bias = tsb[lt*512+i]; wsc = INV_SQRT512; }
  const float4* r4 = (const float4*)row;
  const float4* w4 = (const float4*)(wlat + b*512);
  float acc = 0.f;
  #pragma unroll 4
  for(int k = 0; k < 128; k++){
    float4 a = w4[k], c = r4[k];
    acc += a.x*c.x + a.y*c.y + a.z*c.z + a.w*c.w;
  }
  float s = (acc*INV_SQRT512 + bias) * wsc;
  if(l < 9) s_conv[((size_t)l*32 + b)*512 + i] = s;
  else      s_trgb[((size_t)(l-9)*32 + b)*512 + i] = s;
}

// ---------------- wsq[l,o,i] = sum over 9 taps of w^2 -----------------------
__global__ void k_wsq(const float* __restrict__ cw, float* __restrict__ wsq){
  int gid = blockIdx.x*256 + threadIdx.x;        // 9*512*512
  const float* p = cw + (size_t)gid*9;
  float a = 0.f;
  #pragma unroll
  for(int t = 0; t < 9; t++){ float v = p[t]; a += v*v; }
  wsq[gid] = a;
}

// ---------------- demod d[l,b,o] ---------------------------------------------
__global__ void k_demod(const float* __restrict__ s_conv, const float* __restrict__ wsq,
                        float* __restrict__ d_conv){
  __shared__ float s2[512];
  int l = blockIdx.x/32, b = blockIdx.x%32, t = threadIdx.x;
  size_t base = ((size_t)l*32 + b)*512;
  float v0 = s_conv[base + t], v1 = s_conv[base + t + 256];
  s2[t] = v0*v0; s2[t+256] = v1*v1;
  __syncthreads();
  for(int oo = 0; oo < 2; oo++){
    int o = t + oo*256;
    const float4* wr = (const float4*)(wsq + ((size_t)l*512 + o)*512);
    float acc = 0.f;
    #pragma unroll 4
    for(int k = 0; k < 128; k++){
      float4 w = wr[k];
      acc += w.x*s2[4*k] + w.y*s2[4*k+1] + w.z*s2[4*k+2] + w.w*s2[4*k+3];
    }
    d_conv[base + o] = rsqrtf(acc + 1e-8f);
  }
}

// ---------------- torgb compensation ratio ----------------------------------
__global__ void k_ratio(const float* __restrict__ s_conv, const float* __restrict__ s_trgb,
                        float* __restrict__ rat){
  int gid = blockIdx.x*256 + threadIdx.x;        // 5*32*512 = 81920
  int lt = gid >> 14;
  if(lt >= 4){ rat[gid] = 1.0f; return; }
  int b = (gid >> 9) & 31;
  int i = gid & 511;
  int cl = 1 + 2*lt;                             // consuming conv layer
  float st = s_trgb[((size_t)lt*32 + b)*512 + i];
  float sc = s_conv[((size_t)cl*32 + b)*512 + i];
  rat[gid] = (sc != 0.f) ? st/sc : 0.f;
}

// ---------------- weights: wB[l][tap][o][i] bf16 from cw[l][o][i][tap] -------
__global__ void k_wB(const float* __restrict__ cw, bf16* __restrict__ wB){
  int gid = blockIdx.x*256 + threadIdx.x;        // 9*512*512; (l,o,i)
  const float* p = cw + (size_t)gid*9;
  int l = gid >> 18;
  int oi = gid & 0x3ffff;                        // o*512 + i
  #pragma unroll
  for(int tap = 0; tap < 9; tap++)
    wB[((size_t)(l*9 + tap) << 18) + oi] = __float2bfloat16(p[tap]);
}

// ---------------- const input -> act0 (B,4,4,512) pre-scaled by s_conv[0] ----
__global__ void k_init(const float* __restrict__ ci, const float* __restrict__ s_conv,
                       bf16* __restrict__ act){
  int gid = blockIdx.x*256 + threadIdx.x;        // 32*16*512 = 262144
  int c = gid & 511; int px = (gid >> 9) & 15; int b = gid >> 13;
  act[gid] = __float2bfloat16(ci[c*16 + px] * s_conv[b*512 + c]);
}

// ---------------- main conv: MFMA implicit GEMM ------------------------------
// 128x128 tile, K-step 64 (two 32 halves in LDS), reg-prefetch pipeline with
// raw s_barrier (prefetch vmem stays in flight across barriers).
// UP=false: 3x3 pad1 conv; epilogue d,noise,bias,lrelu,next-scale.
// UP=true : parity-class transposed conv (blockIdx.z = class); epilogue d only,
//           scatter-writes u[2y+py][2x+px].
template<bool UP>
__global__ __launch_bounds__(256, 2)
void k_conv(const bf16* __restrict__ act, const bf16* __restrict__ wL,
            const float* __restrict__ dL, const float* __restrict__ noise,
            const float* __restrict__ nw_ptr, const float* __restrict__ ab,
            const float* __restrict__ sN, bf16* __restrict__ outp,
            int Hin, int Mblocks){
  // n-inner 1D grid + bijective XCD swizzle (gridDim.x is a multiple of 8)
  const int q8 = gridDim.x >> 3;
  const int swz = (blockIdx.x & 7)*q8 + (blockIdx.x >> 3);
  const int nb = swz & 3, mb = swz >> 2;
  if(mb >= Mblocks) return;
  const int mbase = mb*128, nbase = nb*128;

  int py = 0, px = 0;
  int OHy, OHx;
  if(UP){
    int cls = blockIdx.z; py = cls >> 1; px = cls & 1;
    OHy = Hin + 1 - py; OHx = Hin + 1 - px;      // class output dims
  } else {
    OHy = Hin; OHx = Hin;
  }
  const int pixN = OHy*OHx;
  const int Mtot = NB*pixN;
  if(mbase >= Mtot) return;

  __shared__ short As[2][128*40];                // [k-half][row*40 + k] pad 40
  __shared__ short Bs[2][128*40];
  const int t = threadIdx.x;
  const int slot = t & 3;                        // k sub-slot (8 bf16)
  const int rowq[2] = {t >> 2, (t >> 2) + 64};

  int gb[2], gY[2], gX[2]; bool mval[2];
  #pragma unroll
  for(int q = 0; q < 2; q++){
    int m = mbase + rowq[q];
    mval[q] = (m < Mtot);
    int mm = mval[q] ? m : 0;
    gb[q] = mm / pixN; int rem = mm % pixN; gY[q] = rem / OHx; gX[q] = rem % OHx;
  }

  // wave fragment geometry (4 waves, 2x2 over 128x128)
  const int wid = t >> 6;
  const int mrow0 = (wid >> 1)*64;
  const int ncol0 = (wid & 1)*64;
  const int lr = t & 15;
  const int ks = (t & 63) >> 4;

  f32x4 acc[4][4];
  #pragma unroll
  for(int i = 0; i < 4; i++)
    #pragma unroll
    for(int j = 0; j < 4; j++) acc[i][j] = (f32x4){0.f,0.f,0.f,0.f};

  // tap lists (parity-valid subset for UP; all 9 otherwise)
  int dyl[3], dxl[3], ndy, ndx;
  if(UP){
    if(py == 0){ dyl[0]=0; dyl[1]=2; ndy=2; } else { dyl[0]=1; ndy=1; }
    if(px == 0){ dxl[0]=0; dxl[1]=2; ndx=2; } else { dxl[0]=1; ndx=1; }
  } else {
    dyl[0]=0; dyl[1]=1; dyl[2]=2; ndy=3;
    dxl[0]=0; dxl[1]=1; dxl[2]=2; ndx=3;
  }
  const int TT = ndy*ndx;

  for(int tt = 0; tt < TT; tt++){
    const int dy = dyl[tt/ndx], dx = dxl[tt%ndx];
    const int tap = dy*3 + dx;
    const bf16* aptr[2]; bool aok[2];
    #pragma unroll
    for(int q = 0; q < 2; q++){
      aok[q] = false; aptr[q] = act;
      if(mval[q]){
        int yy, xx;
        if(UP){ yy = gY[q] - ((dy - py) >> 1); xx = gX[q] - ((dx - px) >> 1); }
        else  { yy = gY[q] + dy - 1;           xx = gX[q] + dx - 1; }
        if((unsigned)yy < (unsigned)Hin && (unsigned)xx < (unsigned)Hin){
          aok[q] = true;
          aptr[q] = act + ((size_t)((gb[q]*Hin + yy)*Hin + xx) << 9) + slot*8;
        }
      }
    }
    const bf16* bptr[2];
    #pragma unroll
    for(int q = 0; q < 2; q++)
      bptr[q] = wL + (((size_t)tap*512 + nbase + rowq[q]) << 9) + slot*8;

    // prefetch chunk 0 (64 K = 2 halves)
    uint4 pa[2][2], pb[2][2];
    #pragma unroll
    for(int q = 0; q < 2; q++)
      #pragma unroll
      for(int h = 0; h < 2; h++){
        pa[q][h] = aok[q] ? *(const uint4*)(aptr[q] + h*32) : make_uint4(0u,0u,0u,0u);
        pb[q][h] = *(const uint4*)(bptr[q] + h*32);
      }

    #pragma unroll
    for(int c = 0; c < 8; c++){
      asm volatile("" ::: "memory");
      __builtin_amdgcn_s_barrier();              // LDS free (prev reads done)
      #pragma unroll
      for(int q = 0; q < 2; q++)
        #pragma unroll
        for(int h = 0; h < 2; h++){
          *(uint4*)&As[h][rowq[q]*40 + slot*8] = pa[q][h];
          *(uint4*)&Bs[h][rowq[q]*40 + slot*8] = pb[q][h];
        }
      uint4 na[2][2], nb4[2][2];
      if(c < 7){
        const int koff = (c+1)*64;
        #pragma unroll
        for(int q = 0; q < 2; q++)
          #pragma unroll
          for(int h = 0; h < 2; h++){
            na[q][h]  = aok[q] ? *(const uint4*)(aptr[q] + koff + h*32) : make_uint4(0u,0u,0u,0u);
            nb4[q][h] = *(const uint4*)(bptr[q] + koff + h*32);
          }
      }
      asm volatile("s_waitcnt lgkmcnt(0)" ::: "memory");  // my LDS writes done
      __builtin_amdgcn_s_barrier();              // tile ready; prefetch in flight
      #pragma unroll
      for(int h = 0; h < 2; h++){
        bf16x8 af[4], bfr[4];
        #pragma unroll
        for(int f = 0; f < 4; f++){
          af[f]  = *(const bf16x8*)&As[h][(mrow0 + f*16 + lr)*40 + ks*8];
          bfr[f] = *(const bf16x8*)&Bs[h][(ncol0 + f*16 + lr)*40 + ks*8];
        }
        #pragma unroll
        for(int mf = 0; mf < 4; mf++)
          #pragma unroll
          for(int nf = 0; nf < 4; nf++)
            acc[mf][nf] = __builtin_amdgcn_mfma_f32_16x16x32_bf16(af[mf], bfr[nf], acc[mf][nf], 0, 0, 0);
      }
      if(c < 7){
        #pragma unroll
        for(int q = 0; q < 2; q++)
          #pragma unroll
          for(int h = 0; h < 2; h++){ pa[q][h] = na[q][h]; pb[q][h] = nb4[q][h]; }
      }
    }
  }

  // epilogue: C/D frag mapping col=lane&15, row=(lane>>4)*4+reg  [m89-verified]
  const float nwv = UP ? 0.f : *nw_ptr;
  const int U = 2*Hin + 1;
  #pragma unroll
  for(int mf = 0; mf < 4; mf++){
    #pragma unroll
    for(int r = 0; r < 4; r++){
      int m = mbase + mrow0 + mf*16 + ks*4 + r;
      if(m >= Mtot) continue;
      int b = m / pixN; int rem = m % pixN; int y = rem / OHx, x = rem % OHx;
      const float* drow = dL + b*512;
      bf16* orow;
      float nz = 0.f; const float* srow = nullptr;
      if(UP){
        orow = outp + (((size_t)((b*U + 2*y + py))*U + (2*x + px)) << 9);
      } else {
        nz = nwv * noise[(b*OHy + y)*OHx + x];
        srow = sN + b*512;
        orow = outp + ((size_t)m << 9);
      }
      #pragma unroll
      for(int nf = 0; nf < 4; nf++){
        int n = nbase + ncol0 + nf*16 + lr;
        float val = acc[mf][nf][r] * drow[n];
        if(!UP) val = lrelu_s2(val + nz + ab[n]) * srow[n];
        orow[n] = __float2bfloat16(val);
      }
    }
  }
}

// ---------------- 4x4 blur + noise + bias + act + next-scale -----------------
__global__ void k_blur(const bf16* __restrict__ u, const float* __restrict__ noise,
                       const float* __restrict__ nw_ptr, const float* __restrict__ ab,
                       const float* __restrict__ sN, bf16* __restrict__ act, int O){
  const int U = O + 1;
  size_t gid = (size_t)blockIdx.x*256 + threadIdx.x;
  size_t total = (size_t)NB*O*O*128;
  if(gid >= total) return;
  int c4 = gid & 127;
  size_t pix = gid >> 7;
  int X = pix % O; int Y = (pix/O) % O; int b = pix/((size_t)O*O);
  const float k1[4] = {1.f, 3.f, 3.f, 1.f};
  float4 a = make_float4(0.f,0.f,0.f,0.f);
  #pragma unroll
  for(int ky = 0; ky < 4; ky++){
    int yy = Y + ky - 1; if(yy < 0 || yy >= U) continue;
    #pragma unroll
    for(int kx = 0; kx < 4; kx++){
      int xx = X + kx - 1; if(xx < 0 || xx >= U) continue;
      float w = k1[ky]*k1[kx]*(1.f/16.f);
      uint2 u2 = *(const uint2*)(u + (((size_t)(b*U + yy)*U + xx) << 9) + c4*4);
      a.x += w*bf_lo(u2.x); a.y += w*bf_hi(u2.x);
      a.z += w*bf_lo(u2.y); a.w += w*bf_hi(u2.y);
    }
  }
  float nz = (*nw_ptr) * noise[(b*O + Y)*O + X];
  const float* abp4 = ab + c4*4;
  float4 s4 = *(const float4*)(sN + b*512 + c4*4);
  uint2 pk;
  pk.x = packbf2(lrelu_s2(a.x + nz + abp4[0])*s4.x, lrelu_s2(a.y + nz + abp4[1])*s4.y);
  pk.y = packbf2(lrelu_s2(a.z + nz + abp4[2])*s4.z, lrelu_s2(a.w + nz + abp4[3])*s4.w);
  *(uint2*)(act + (pix << 9) + c4*4) = pk;
}

// ---------------- toRGB (1x1 mod conv, no demod) -> NCHW skip ----------------
__global__ void k_torgb(const bf16* __restrict__ act, const float* __restrict__ tw,
                        const float* __restrict__ ratL, const float* __restrict__ tbias,
                        float* __restrict__ dst, int H, int lt, int addflag){
  int wid = threadIdx.x >> 6, lane = threadIdx.x & 63;
  int pix = blockIdx.x*4 + wid;
  int npix = NB*H*H;
  if(pix >= npix) return;
  int b = pix/(H*H);
  const bf16* ap = act + ((size_t)pix << 9);
  const float* rp = ratL + (size_t)b*512;
  const float* w0 = tw + ((size_t)lt*3 + 0)*512;
  const float* w1 = tw + ((size_t)lt*3 + 1)*512;
  const float* w2 = tw + ((size_t)lt*3 + 2)*512;
  float a0 = 0.f, a1 = 0.f, a2 = 0.f;
  #pragma unroll
  for(int j = 0; j < 8; j++){
    int i = lane + j*64;
    float xs = __bfloat162float(ap[i])*rp[i];
    a0 += xs*w0[i]; a1 += xs*w1[i]; a2 += xs*w2[i];
  }
  for(int off = 32; off > 0; off >>= 1){
    a0 += __shfl_xor(a0, off);
    a1 += __shfl_xor(a1, off);
    a2 += __shfl_xor(a2, off);
  }
  if(lane == 0){
    int rem = pix % (H*H);
    size_t o0 = ((size_t)(b*3 + 0)*H*H) + rem;
    size_t o1 = ((size_t)(b*3 + 1)*H*H) + rem;
    size_t o2 = ((size_t)(b*3 + 2)*H*H) + rem;
    float b0 = tbias[lt*3+0], b1 = tbias[lt*3+1], b2 = tbias[lt*3+2];
    if(addflag){ dst[o0] += a0 + b0; dst[o1] += a1 + b1; dst[o2] += a2 + b2; }
    else       { dst[o0]  = a0 + b0; dst[o1]  = a1 + b1; dst[o2]  = a2 + b2; }
  }
}

// ---------------- skip upsample 2x (NCHW, 3ch) -------------------------------
__global__ void k_skipup(const float* __restrict__ sin, float* __restrict__ sout, int h){
  const int O = 2*h;
  int gid = blockIdx.x*256 + threadIdx.x;
  int total = NB*3*O*O;
  if(gid >= total) return;
  int X = gid % O; int Y = (gid/O) % O; int c = (gid/(O*O)) % 3; int b = gid/(3*O*O);
  const float k1[4] = {1.f, 3.f, 3.f, 1.f};
  float acc = 0.f;
  for(int ky = (Y & 1); ky < 4; ky += 2){
    int ty = Y + ky - 2;
    if(ty < 0) continue;
    int y = ty >> 1; if(y >= h) continue;
    for(int kx = (X & 1); kx < 4; kx += 2){
      int tx = X + kx - 2;
      if(tx < 0) continue;
      int x = tx >> 1; if(x >= h) continue;
      acc += k1[ky]*k1[kx]*(1.f/16.f) * sin[((size_t)(b*3 + c)*h + y)*h + x];
    }
  }
  sout[gid] = acc;
}

// ---------------------------------------------------------------------------
extern "C" void kernel_launch(void* const* d_in, const int* in_sizes, int n_in,
                              void* d_out, int out_size, void* d_ws, size_t ws_size,
                              hipStream_t stream){
  const float* z     = (const float*)d_in[0];
  const float* mlp_w = (const float*)d_in[1];
  const float* mlp_b = (const float*)d_in[2];
  const float* cinp  = (const float*)d_in[3];
  const float* conv_w= (const float*)d_in[4];
  const float* csw   = (const float*)d_in[5];
  const float* csb   = (const float*)d_in[6];
  const float* nwp   = (const float*)d_in[7];
  const float* abp   = (const float*)d_in[8];
  const float* tw    = (const float*)d_in[9];
  const float* tsw   = (const float*)d_in[10];
  const float* tsb   = (const float*)d_in[11];
  const float* tb    = (const float*)d_in[12];
  const float* noise[9];
  for(int i = 0; i < 9; i++) noise[i] = (const float*)d_in[13 + i];

  // workspace layout (bytes)
  const size_t UMAX = (size_t)32*65*65*512;       // 69,206,016 elems
  char* base = (char*)d_ws;
  size_t off = 0;
  bf16* buf0 = (bf16*)(base + off); off += UMAX*2;                 // 138,412,032
  bf16* buf1 = (bf16*)(base + off); off += UMAX*2;                 // 138,412,032
  bf16* wB   = (bf16*)(base + off); off += (size_t)9*9*512*512*2;  //  42,467,328
  float* wsq = (float*)(base + off); off += (size_t)9*512*512*4;   //   9,437,184
  float* wlat= (float*)(base + off); off += (size_t)32*512*4;
  float* sconv=(float*)(base + off); off += (size_t)9*32*512*4;
  float* dconv=(float*)(base + off); off += (size_t)9*32*512*4;
  float* strgb=(float*)(base + off); off += (size_t)5*32*512*4;
  float* rat  =(float*)(base + off); off += (size_t)5*32*512*4;
  float* skipA=(float*)(base + off); off += (size_t)32*3*64*64*4;
  float* skipB=(float*)(base + off); off += (size_t)32*3*64*64*4;
  if(ws_size < off){
    fprintf(stderr, "kernel_launch: ws too small (%zu < %zu)\n", ws_size, off);
    return;
  }
  float* out = (float*)d_out;

  // prep
  k_mapping<<<32, 256, 0, stream>>>(z, mlp_w, mlp_b, wlat);
  k_styles <<<896, 256, 0, stream>>>(wlat, csw, csb, tsw, tsb, sconv, strgb);
  k_wsq    <<<9216, 256, 0, stream>>>(conv_w, wsq);
  k_demod  <<<288, 256, 0, stream>>>(sconv, wsq, dconv);
  k_ratio  <<<320, 256, 0, stream>>>(sconv, strgb, rat);
  k_wB     <<<9216, 256, 0, stream>>>(conv_w, wB);
  k_init   <<<1024, 256, 0, stream>>>(cinp, sconv, buf0);

  auto conv_noup = [&](const bf16* in, bf16* o, int H, int layer, const float* sN){
    int M = 32*H*H; int Mb = (M + 127)/128;
    int Gx = ((Mb*4 + 7)/8)*8;
    k_conv<false><<<dim3(Gx,1,1), 256, 0, stream>>>(in, wB + ((size_t)layer*9 << 18),
        dconv + (size_t)layer*NB*512, noise[layer], nwp + layer, abp + layer*512, sN, o, H, Mb);
  };
  auto conv_up = [&](const bf16* in, bf16* o, int Hin, int layer){
    int Mmax = 32*(Hin+1)*(Hin+1); int Mb = (Mmax + 127)/128;
    int Gx = ((Mb*4 + 7)/8)*8;
    k_conv<true><<<dim3(Gx,1,4), 256, 0, stream>>>(in, wB + ((size_t)layer*9 << 18),
        dconv + (size_t)layer*NB*512, nullptr, nullptr, nullptr, nullptr, o, Hin, Mb);
  };
  auto blur = [&](const bf16* u, bf16* o, int O, int layer, const float* sN){
    size_t total = (size_t)32*O*O*128;
    k_blur<<<(unsigned)((total + 255)/256), 256, 0, stream>>>(u, noise[layer], nwp + layer,
        abp + layer*512, sN, o, O);
  };
  auto torgb = [&](const bf16* act, float* dst, int H, int lt, int add){
    int npix = 32*H*H;
    k_torgb<<<(npix + 3)/4, 256, 0, stream>>>(act, tw, rat + (size_t)lt*NB*512, tb, dst, H, lt, add);
  };
  auto skipup = [&](const float* sin, float* sout, int h){
    int total = 32*3*(2*h)*(2*h);
    k_skipup<<<(total + 255)/256, 256, 0, stream>>>(sin, sout, h);
  };

  const float* S = sconv;   // s rows per layer: S + layer*NB*512
  const float* sT4 = strgb + (size_t)4*NB*512;

  // layer 0 @4   (output scaled by s1)
  conv_noup(buf0, buf1, 4, 0, S + (size_t)1*NB*512);
  torgb(buf1, skipA, 4, 0, 0);

  // r=0: 4->8
  conv_up(buf1, buf0, 4, 1);
  blur(buf0, buf1, 8, 1, S + (size_t)2*NB*512);
  conv_noup(buf1, buf0, 8, 2, S + (size_t)3*NB*512);
  skipup(skipA, skipB, 4);
  torgb(buf0, skipB, 8, 1, 1);

  // r=1: 8->16
  conv_up(buf0, buf1, 8, 3);
  blur(buf1, buf0, 16, 3, S + (size_t)4*NB*512);
  conv_noup(buf0, buf1, 16, 4, S + (size_t)5*NB*512);
  skipup(skipB, skipA, 8);
  torgb(buf1, skipA, 16, 2, 1);

  // r=2: 16->32
  conv_up(buf1, buf0, 16, 5);
  blur(buf0, buf1, 32, 5, S + (size_t)6*NB*512);
  conv_noup(buf1, buf0, 32, 6, S + (size_t)7*NB*512);
  skipup(skipA, skipB, 16);
  torgb(buf0, skipB, 32, 3, 1);

  // r=3: 32->64
  conv_up(buf0, buf1, 32, 7);
  blur(buf1, buf0, 64, 7, S + (size_t)8*NB*512);
  conv_noup(buf0, buf1, 64, 8, sT4);            // last conv: scale by s_trgb4
  skipup(skipB, out, 32);                        // overwrite d_out (poison-safe)
  torgb(buf1, out, 64, 4, 1);                    // final skip add -> d_out
}